// Round 3
// baseline (3489.062 us; speedup 1.0000x reference)
//
#include <hip/hip_runtime.h>
#include <stdint.h>

typedef __bf16 bf16x8 __attribute__((ext_vector_type(8)));
typedef float  f32x4  __attribute__((ext_vector_type(4)));

__device__ __forceinline__ uint16_t f2b(float f) {
  uint32_t u = __float_as_uint(f);
  return (uint16_t)((u + 0x7FFFu + ((u >> 16) & 1u)) >> 16);
}
__device__ __forceinline__ float b2f(uint16_t h) {
  return __uint_as_float(((uint32_t)h) << 16);
}
__device__ __forceinline__ uint4 pack8f(float4 a, float4 b) {
  uint4 r;
  r.x = (uint32_t)f2b(a.x) | ((uint32_t)f2b(a.y) << 16);
  r.y = (uint32_t)f2b(a.z) | ((uint32_t)f2b(a.w) << 16);
  r.z = (uint32_t)f2b(b.x) | ((uint32_t)f2b(b.y) << 16);
  r.w = (uint32_t)f2b(b.z) | ((uint32_t)f2b(b.w) << 16);
  return r;
}

typedef const __attribute__((address_space(1))) unsigned int* gasp;
typedef __attribute__((address_space(3))) unsigned int* lasp;
__device__ __forceinline__ void glds16(const uint16_t* g, uint16_t* l) {
  __builtin_amdgcn_global_load_lds((gasp)(const void*)g, (lasp)(void*)l, 16, 0, 0);
}

// -------------------------------------------------------------------------
// Dtype detector (bf16-packed vs fp32 buffers), verified working in round 2.
__global__ void detect_kernel(const uint32_t* __restrict__ wproj, int* flag) {
  __shared__ int cnt;
  if (threadIdx.x == 0) cnt = 0;
  __syncthreads();
  int local = 0;
  for (int i = threadIdx.x; i < 1024; i += 256) {
    float v = __uint_as_float((wproj[i] & 0xFFFFu) << 16);
    float av = fabsf(v);
    if (av > 1e-4f && av < 0.5f) local++;
  }
  atomicAdd(&cnt, local);
  __syncthreads();
  if (threadIdx.x == 0) flag[0] = (cnt > 512) ? 1 : 0;
}

__global__ void convert_kernel(const void* __restrict__ src,
                               uint16_t* __restrict__ dst,
                               const int* __restrict__ flagp) {
  int i = blockIdx.x * 256 + threadIdx.x;
  if (*flagp) {
    ((uint4*)dst)[i] = ((const uint4*)src)[i];
  } else {
    const float* s = (const float*)src + (size_t)i * 8;
    ((uint4*)dst)[i] = pack8f(*(const float4*)s, *(const float4*)(s + 4));
  }
}

__global__ void word_kernel(const int* __restrict__ ids,
                            const void* __restrict__ embed,
                            uint16_t* __restrict__ word,
                            const int* __restrict__ flagp) {
  int c = blockIdx.x * 256 + threadIdx.x;
  int b = c >> 6, off = c & 63;
  size_t row = (size_t)ids[b] * 512;
  if (*flagp) {
    ((uint4*)word)[c] = ((const uint4*)((const uint16_t*)embed + row))[off];
  } else {
    const float* s = (const float*)embed + row + (size_t)off * 8;
    ((uint4*)word)[c] = pack8f(*(const float4*)s, *(const float4*)(s + 4));
  }
}

__global__ void bias2_kernel(const void* __restrict__ bih,
                             const void* __restrict__ bhh,
                             const void* __restrict__ bproj,
                             const uint16_t* __restrict__ Wihb,
                             float* __restrict__ bias2,
                             const int* __restrict__ flagp) {
  int j = blockIdx.x * 256 + threadIdx.x;
  int fl = *flagp;
  float s;
  if (fl) s = b2f(((const uint16_t*)bih)[j]) + b2f(((const uint16_t*)bhh)[j]);
  else    s = ((const float*)bih)[j] + ((const float*)bhh)[j];
  const uint16_t* wrow = Wihb + (size_t)j * 1024;
  float acc = 0.f;
  for (int f = 0; f < 512; f++) {
    float bp = fl ? b2f(((const uint16_t*)bproj)[f]) : ((const float*)bproj)[f];
    acc += bp * b2f(wrow[f]);
  }
  bias2[j] = s + acc;
}

// -------------------------------------------------------------------------
// C[M,N] = A[M,K] @ Bt[N,K]^T, 128x128 tile, BK=32, global_load_lds staging.
// MODE 0: C bf16 (ldc). MODE 2: C fp32 (ldc), += wg[col].
// MODE 1: full xg: m -> b=m/80, t=m%80; C[(t*512+b)*2048+col] fp32 += wg[b*2048+col].
template <int MODE, bool APOLY>
__global__ __launch_bounds__(256, 2)
void gemm_bt(const void* __restrict__ Av, int lda,
             const uint16_t* __restrict__ Bt, int ldb,
             void* __restrict__ Cout, int ldc, int K,
             const float* __restrict__ wg,
             const int* __restrict__ flagp) {
  __shared__ __align__(16) uint16_t As[128 * 32];
  __shared__ __align__(16) uint16_t Bs[128 * 32];
  const int tid = threadIdx.x;
  const int bm = blockIdx.y * 128, bn = blockIdx.x * 128;
  const int wid = tid >> 6, lane = tid & 63;
  const int wm = (wid >> 1) * 64, wn = (wid & 1) * 64;
  const int lrow = lane & 15, quad = lane >> 4;
  const int srow = tid >> 2, scol = (tid & 3) * 8;
  const bool a_bf16 = APOLY ? (*flagp != 0) : true;
  const size_t gr0 = bm + srow, gr1 = bm + 64 + srow;
  f32x4 acc[4][4] = {};

  for (int kb = 0; kb < K; kb += 32) {
    __syncthreads();
    if (a_bf16) {
      glds16((const uint16_t*)Av + gr0 * lda + kb + scol, As + (size_t)tid * 8);
      glds16((const uint16_t*)Av + gr1 * lda + kb + scol, As + 2048 + (size_t)tid * 8);
    } else {
      const float* p0 = (const float*)Av + gr0 * lda + kb + scol;
      const float* p1 = (const float*)Av + gr1 * lda + kb + scol;
      *(uint4*)(As + srow * 32 + scol) = pack8f(*(const float4*)p0, *(const float4*)(p0 + 4));
      *(uint4*)(As + (64 + srow) * 32 + scol) = pack8f(*(const float4*)p1, *(const float4*)(p1 + 4));
    }
    glds16(Bt + (size_t)(bn + srow) * ldb + kb + scol, Bs + (size_t)tid * 8);
    glds16(Bt + (size_t)(bn + 64 + srow) * ldb + kb + scol, Bs + 2048 + (size_t)tid * 8);
    asm volatile("s_waitcnt vmcnt(0)" ::: "memory");
    __syncthreads();
    bf16x8 af[4], bfr[4];
#pragma unroll
    for (int i = 0; i < 4; i++) {
      af[i]  = *reinterpret_cast<const bf16x8*>(As + (wm + i * 16 + lrow) * 32 + quad * 8);
      bfr[i] = *reinterpret_cast<const bf16x8*>(Bs + (wn + i * 16 + lrow) * 32 + quad * 8);
    }
#pragma unroll
    for (int i = 0; i < 4; i++)
#pragma unroll
      for (int j = 0; j < 4; j++)
        acc[i][j] = __builtin_amdgcn_mfma_f32_16x16x32_bf16(af[i], bfr[j], acc[i][j], 0, 0, 0);
  }

  if constexpr (MODE == 0) {
    uint16_t* C = (uint16_t*)Cout;
#pragma unroll
    for (int i = 0; i < 4; i++) {
      int row = bm + wm + i * 16 + quad * 4;
#pragma unroll
      for (int j = 0; j < 4; j++) {
        int col = bn + wn + j * 16 + lrow;
#pragma unroll
        for (int r = 0; r < 4; r++)
          C[(size_t)(row + r) * ldc + col] = f2b(acc[i][j][r]);
      }
    }
  } else if constexpr (MODE == 2) {
    float* C = (float*)Cout;
#pragma unroll
    for (int i = 0; i < 4; i++) {
      int row = bm + wm + i * 16 + quad * 4;
#pragma unroll
      for (int j = 0; j < 4; j++) {
        int col = bn + wn + j * 16 + lrow;
        float bias = wg[col];
#pragma unroll
        for (int r = 0; r < 4; r++)
          C[(size_t)(row + r) * ldc + col] = acc[i][j][r] + bias;
      }
    }
  } else {  // MODE 1
    float* C = (float*)Cout;
#pragma unroll
    for (int i = 0; i < 4; i++) {
#pragma unroll
      for (int r = 0; r < 4; r++) {
        int m = bm + wm + i * 16 + quad * 4 + r;
        int b = m / 80;
        int t = m - b * 80;
        size_t orow = (size_t)t * 512 + b;
#pragma unroll
        for (int j = 0; j < 4; j++) {
          int col = bn + wn + j * 16 + lrow;
          C[orow * 2048 + col] = acc[i][j][r] + wg[(size_t)b * 2048 + col];
        }
      }
    }
  }
}

// -------------------------------------------------------------------------
// Persistent recurrence: 128 WGs x 256 threads, all 80 steps in one launch.
// WG (bg=blk>>5, cg=blk&31): batch rows [bg*128, +128), h-cols [cg*16, +16).
// Wave wv: 32 batch rows (2 m-tiles) x 16 h-cols x 4 gates; c kept in VGPRs.
// W_hh tile (64 rows x 512) in LDS, XOR-swizzled: phys_k = k ^ ((row&7)<<3).
__global__ __launch_bounds__(256, 1)
void rec_kernel(const float* __restrict__ xg,       // [80,512,2048] f32
                const uint16_t* __restrict__ Whh,   // [2048,512] bf16
                uint16_t* __restrict__ hb0, uint16_t* __restrict__ hb1,
                void* __restrict__ out,
                const int* __restrict__ flagp,
                int* __restrict__ bar) {            // bar[0]=cnt, bar[1]=gen
  __shared__ __align__(16) uint16_t Ws[64 * 512];   // 64 KB
  const int tid = threadIdx.x;
  const int wv = tid >> 6, lane = tid & 63;
  const int lrow = lane & 15, quad = lane >> 4;
  const int cg = blockIdx.x & 31;
  const int bO = (blockIdx.x >> 5) * 128 + wv * 32;
  const int hh = cg * 16 + lrow;
  const int fl = *flagp;

  // stage W_hh tile: rows g*16+c -> global row g*512 + cg*16 + c
  for (int it = 0; it < 16; it++) {
    int chunk = it * 256 + tid;
    int row = chunk >> 6;
    int k0 = (chunk & 63) << 3;
    int grow = (row >> 4) * 512 + cg * 16 + (row & 15);
    uint4 v = *(const uint4*)(Whh + (size_t)grow * 512 + k0);
    *(uint4*)(Ws + row * 512 + (k0 ^ ((row & 7) << 3))) = v;
  }
  __syncthreads();

  float creg[2][4];
#pragma unroll
  for (int i = 0; i < 2; i++)
#pragma unroll
    for (int r = 0; r < 4; r++) creg[i][r] = 0.f;

  for (int t = 0; t < 80; t++) {
    const uint16_t* hp = (t & 1) ? hb1 : hb0;
    uint16_t* hn = (t & 1) ? hb0 : hb1;
    f32x4 acc[2][4] = {};
#pragma unroll
    for (int ki = 0; ki < 16; ki++) {
      bf16x8 af[2], bfr[4];
#pragma unroll
      for (int i = 0; i < 2; i++)
        af[i] = *reinterpret_cast<const bf16x8*>(
            hp + (size_t)(bO + i * 16 + lrow) * 512 + ki * 32 + quad * 8);
#pragma unroll
      for (int g = 0; g < 4; g++) {
        int row = g * 16 + lrow;
        int k0 = (ki * 32 + quad * 8) ^ ((row & 7) << 3);
        bfr[g] = *reinterpret_cast<const bf16x8*>(Ws + row * 512 + k0);
      }
#pragma unroll
      for (int i = 0; i < 2; i++)
#pragma unroll
        for (int g = 0; g < 4; g++)
          acc[i][g] = __builtin_amdgcn_mfma_f32_16x16x32_bf16(af[i], bfr[g], acc[i][g], 0, 0, 0);
    }
#pragma unroll
    for (int i = 0; i < 2; i++) {
#pragma unroll
      for (int r = 0; r < 4; r++) {
        int b = bO + i * 16 + quad * 4 + r;
        const float* xr = xg + ((size_t)t * 512 + b) * 2048 + hh;
        float pi = acc[i][0][r] + xr[0];
        float pf = acc[i][1][r] + xr[512];
        float pg = acc[i][2][r] + xr[1024];
        float po = acc[i][3][r] + xr[1536];
        float si = 1.f / (1.f + __expf(-pi));
        float sf = 1.f / (1.f + __expf(-pf));
        float so = 1.f / (1.f + __expf(-po));
        float tg = 1.f - 2.f / (__expf(2.f * pg) + 1.f);
        float cn = sf * creg[i][r] + si * tg;
        creg[i][r] = cn;
        float hv = so * (1.f - 2.f / (__expf(2.f * cn) + 1.f));
        uint16_t hbv = f2b(hv);
        hn[(size_t)b * 512 + hh] = hbv;
        size_t oi = ((size_t)b * 80 + t) * 512 + hh;
        if (fl) ((uint16_t*)out)[oi] = hbv;
        else    ((float*)out)[oi] = hv;
      }
    }
    // ---- grid barrier (sense = generation counter) ----
    __builtin_amdgcn_fence(__ATOMIC_RELEASE, "agent");
    __syncthreads();
    if (tid == 0) {
      int a = __hip_atomic_fetch_add(&bar[0], 1, __ATOMIC_ACQ_REL, __HIP_MEMORY_SCOPE_AGENT);
      if (a == 127) {
        __hip_atomic_store(&bar[0], 0, __ATOMIC_RELAXED, __HIP_MEMORY_SCOPE_AGENT);
        __hip_atomic_fetch_add(&bar[1], 1, __ATOMIC_RELEASE, __HIP_MEMORY_SCOPE_AGENT);
      } else {
        while (__hip_atomic_load(&bar[1], __ATOMIC_ACQUIRE, __HIP_MEMORY_SCOPE_AGENT) <= t)
          __builtin_amdgcn_s_sleep(1);
      }
    }
    __syncthreads();
    __builtin_amdgcn_fence(__ATOMIC_ACQUIRE, "agent");
  }
}

// -------------------------------------------------------------------------
extern "C" void kernel_launch(void* const* d_in, const int* in_sizes, int n_in,
                              void* d_out, int out_size, void* d_ws, size_t ws_size,
                              hipStream_t stream) {
  const void* enc   = d_in[0];            // [512,80,1024]
  const int*  ids   = (const int*)d_in[1];
  const void* Wproj = d_in[2];            // [1024,512]
  const void* bproj = d_in[3];
  const void* embed = d_in[4];            // [10000,512]
  const void* Wih   = d_in[5];            // [2048,1024]
  const void* Whh   = d_in[6];            // [2048,512]
  const void* bih   = d_in[7];
  const void* bhh   = d_in[8];

  uint8_t* w = (uint8_t*)d_ws;
  int*      bar    = (int*)w;                    // 256 B
  int*      flag   = (int*)(w + 256);
  float*    bias2  = (float*)(w + 16384);
  float*    wgates = (float*)(w + 32768);        // [512,2048] f32, 4 MB
  uint16_t* combT  = (uint16_t*)(w + 4227072);   // [2048,1024] bf16, 4 MB
  uint16_t* Wihb   = (uint16_t*)(w + 8421376);   // [2048,1024] bf16, 4 MB
  uint16_t* Whhb   = (uint16_t*)(w + 12615680);  // [2048,512] bf16, 2 MB
  uint16_t* Wprojb = (uint16_t*)(w + 14712832);  // [1024,512] bf16, 1 MB
  uint16_t* word   = (uint16_t*)(w + 15761408);  // [512,512] bf16, 512 KB
  uint16_t* hbuf0  = (uint16_t*)(w + 16285696);  // 512 KB
  uint16_t* hbuf1  = (uint16_t*)(w + 16809984);  // 512 KB
  float*    xg     = (float*)(w + 33554432);     // [80,512,2048] f32, 320 MB -> ends 352 MB

  detect_kernel<<<1, 256, 0, stream>>>((const uint32_t*)Wproj, flag);
  convert_kernel<<<1024, 256, 0, stream>>>(Wih, Wihb, flag);
  convert_kernel<<<512, 256, 0, stream>>>(Whh, Whhb, flag);
  convert_kernel<<<256, 256, 0, stream>>>(Wproj, Wprojb, flag);
  word_kernel<<<128, 256, 0, stream>>>(ids, embed, word, flag);
  bias2_kernel<<<8, 256, 0, stream>>>(bih, bhh, bproj, Wihb, bias2, flag);

  // combT[j,d] = sum_f W_ih[j,f] * W_proj[d,f]   (M=2048,N=1024,K=512)
  gemm_bt<0, false><<<dim3(8, 16), 256, 0, stream>>>(Wihb, 1024, Wprojb, 512,
                                                     combT, 1024, 512, nullptr, flag);
  // wgates[b,j] = sum_w word[b,w]*W_ih[j,512+w] + bias2[j]  (M=512,N=2048,K=512)
  gemm_bt<2, false><<<dim3(16, 4), 256, 0, stream>>>(word, 512, Wihb + 512, 1024,
                                                     wgates, 2048, 512, bias2, flag);
  // xg[t,b,j] = sum_d enc[b,t,d]*combT[j,d] + wgates[b,j]   (M=40960,N=2048,K=1024)
  gemm_bt<1, true><<<dim3(16, 320), 256, 0, stream>>>(enc, 1024, combT, 1024,
                                                      xg, 2048, 1024, wgates, flag);

  (void)hipMemsetAsync(bar, 0, 256, stream);
  (void)hipMemsetAsync(hbuf0, 0, 512 * 512 * 2, stream);

  rec_kernel<<<128, 256, 0, stream>>>(xg, Whhb, hbuf0, hbuf1, d_out, flag, bar);
}